// Round 1
// baseline (1054.656 us; speedup 1.0000x reference)
//
#include <hip/hip_runtime.h>
#include <math.h>

#define SEQ    4096
#define NFFT   8192
#define DMODEL 1024
#define ORDER  64
#define THREADS 256

// ---------------------------------------------------------------------------
// Twiddle LUT: tw[j] = (cos, sin)(2*pi*j/8192), j in [0, 4096)
// ---------------------------------------------------------------------------
__global__ void tw_init_kernel(float2* __restrict__ tw) {
    int j = blockIdx.x * blockDim.x + threadIdx.x;
    if (j < NFFT / 2) {
        double ang = (2.0 * M_PI / (double)NFFT) * (double)j;
        tw[j] = make_float2((float)cos(ang), (float)sin(ang));
    }
}

// ---------------------------------------------------------------------------
// MLP: H[o][l] = final hidden state (after 3 sin layers), transposed layout.
// One thread per (position, unit); 4 positions per 256-thread block.
// ---------------------------------------------------------------------------
__global__ void mlp_kernel(const float* __restrict__ W1, const float* __restrict__ b1,
                           const float* __restrict__ W2, const float* __restrict__ b2,
                           const float* __restrict__ W3, const float* __restrict__ b3,
                           const float* __restrict__ freq, float* __restrict__ Ht) {
    int o = threadIdx.x & 63;
    int p = threadIdx.x >> 6;          // 0..3
    int l = blockIdx.x * 4 + p;        // 0..4095
    __shared__ float hs[4][ORDER];

    float t   = (float)l / 4095.0f;
    float ang = 1e-4f * (float)(2.0 * M_PI) * (float)l / 4096.0f;
    float z0 = t, z1 = cosf(ang), z2 = -sinf(ang);
    float fo = freq[o];

    float a = z0 * W1[o] + z1 * W1[ORDER + o] + z2 * W1[2 * ORDER + o] + b1[o];
    hs[p][o] = sinf(fo * a);
    __syncthreads();

    a = b2[o];
    #pragma unroll
    for (int i = 0; i < ORDER; i++) a += hs[p][i] * W2[i * ORDER + o];
    float h2 = sinf(fo * a);
    __syncthreads();
    hs[p][o] = h2;
    __syncthreads();

    a = b3[o];
    #pragma unroll
    for (int i = 0; i < ORDER; i++) a += hs[p][i] * W3[i * ORDER + o];
    Ht[o * SEQ + l] = sinf(fo * a);
}

// ---------------------------------------------------------------------------
// FFT helpers (radix-2, in-LDS).
// fft_fwd: DIF, natural input -> bit-reversed output, twiddle e^{-i theta}
// fft_inv: DIT, bit-reversed input -> natural output, twiddle e^{+i theta}
// (no 1/N scaling; folded into the filter spectrum)
// ---------------------------------------------------------------------------
__device__ inline void fft_fwd(float* re, float* im, const float2* __restrict__ tw) {
    for (int s = 0; s < 13; s++) {
        int half = (NFFT / 2) >> s;
        for (int b = threadIdx.x; b < NFFT / 2; b += THREADS) {
            int j  = b & (half - 1);
            int i0 = ((b >> (12 - s)) << (13 - s)) + j;
            int i1 = i0 + half;
            float ur = re[i0], ui = im[i0];
            float vr = re[i1], vi = im[i1];
            float2 w = tw[j << s];                 // (c, s) of +theta
            re[i0] = ur + vr;  im[i0] = ui + vi;
            float dr = ur - vr, di = ui - vi;
            // (dr + i di) * (c - i s)
            re[i1] = dr * w.x + di * w.y;
            im[i1] = di * w.x - dr * w.y;
        }
        __syncthreads();
    }
}

__device__ inline void fft_inv(float* re, float* im, const float2* __restrict__ tw) {
    for (int s = 0; s < 13; s++) {
        int half = 1 << s;
        for (int b = threadIdx.x; b < NFFT / 2; b += THREADS) {
            int j  = b & (half - 1);
            int i0 = ((b >> s) << (s + 1)) + j;
            int i1 = i0 + half;
            float2 w = tw[j << (12 - s)];
            float vr = re[i1], vi = im[i1];
            // v * (c + i s)
            float tr = vr * w.x - vi * w.y;
            float ti = vi * w.x + vr * w.y;
            float ur = re[i0], ui = im[i0];
            re[i0] = ur + tr;  im[i0] = ui + ti;
            re[i1] = ur - tr;  im[i1] = ui - ti;
        }
        __syncthreads();
    }
}

// ---------------------------------------------------------------------------
// Filter build + forward FFT: K_br[d][0..8191] (bit-reversed order, * 1/N)
// ---------------------------------------------------------------------------
__global__ __launch_bounds__(THREADS) void kfft_kernel(const float* __restrict__ Wout,
                                                       const float* __restrict__ Ht,
                                                       const float2* __restrict__ tw,
                                                       float2* __restrict__ Kbr) {
    int d = blockIdx.x;
    __shared__ float re[NFFT], im[NFFT];

    // deltas = abs(linspace(log(.01)/1.5, log(.01)/0.3, 1024))
    const double MIN_D = -3.0701134573253944;
    const double MAX_D = -15.350567286626971;
    float delta = fabsf((float)(MIN_D + (MAX_D - MIN_D) * (double)d / 1023.0));

    for (int l = threadIdx.x; l < SEQ; l += THREADS) {
        float acc = 0.0f;
        #pragma unroll
        for (int o = 0; o < ORDER; o++)
            acc += Ht[o * SEQ + l] * Wout[o * DMODEL + d];
        float t = (float)l / 4095.0f;
        re[l] = acc * expf(-t * delta);
        im[l] = 0.0f;
        re[l + SEQ] = 0.0f;
        im[l + SEQ] = 0.0f;
    }
    __syncthreads();

    fft_fwd(re, im, tw);

    const float scale = 1.0f / (float)NFFT;
    for (int i = threadIdx.x; i < NFFT; i += THREADS) {
        Kbr[(size_t)d * NFFT + i] = make_float2(re[i] * scale, im[i] * scale);
    }
}

// ---------------------------------------------------------------------------
// Main conv kernel: one WG per (channel, batch-pair).
// z = x[b0,d,:] + i x[b1,d,:]  -> FFT -> * K_br[d] -> IFFT ->
// out[b0] = Re + bias*x[b0], out[b1] = Im + bias*x[b1]
// (valid because conv with a real kernel is linear and real->real)
// ---------------------------------------------------------------------------
__global__ __launch_bounds__(THREADS) void conv_kernel(const float* __restrict__ x,
                                                       const float* __restrict__ bias,
                                                       const float2* __restrict__ Kbr,
                                                       const float2* __restrict__ tw,
                                                       float* __restrict__ out) {
    int wg   = blockIdx.x;            // 0..4095
    int d    = wg & (DMODEL - 1);
    int pair = wg >> 10;              // 0..3
    int b0   = 2 * pair, b1 = 2 * pair + 1;

    const float* xa = x + ((size_t)b0 * DMODEL + d) * SEQ;
    const float* xb = x + ((size_t)b1 * DMODEL + d) * SEQ;

    __shared__ float re[NFFT], im[NFFT];

    const float4* xa4 = (const float4*)xa;
    const float4* xb4 = (const float4*)xb;
    float4* re4 = (float4*)re;
    float4* im4 = (float4*)im;

    for (int i = threadIdx.x; i < SEQ / 4; i += THREADS) {
        re4[i] = xa4[i];
        im4[i] = xb4[i];
    }
    float4 z4 = make_float4(0.f, 0.f, 0.f, 0.f);
    for (int i = threadIdx.x; i < SEQ / 4; i += THREADS) {
        re4[i + SEQ / 4] = z4;
        im4[i + SEQ / 4] = z4;
    }
    __syncthreads();

    fft_fwd(re, im, tw);

    const float2* K = Kbr + (size_t)d * NFFT;
    for (int i = threadIdx.x; i < NFFT; i += THREADS) {
        float2 k2 = K[i];
        float zr = re[i], zi = im[i];
        re[i] = zr * k2.x - zi * k2.y;
        im[i] = zr * k2.y + zi * k2.x;
    }
    __syncthreads();

    fft_inv(re, im, tw);

    float bd = bias[d];
    float* oa = out + ((size_t)b0 * DMODEL + d) * SEQ;
    float* ob = out + ((size_t)b1 * DMODEL + d) * SEQ;
    float4* oa4 = (float4*)oa;
    float4* ob4 = (float4*)ob;
    for (int i = threadIdx.x; i < SEQ / 4; i += THREADS) {
        float4 r = re4[i], xv = xa4[i];
        float4 s = im4[i], xw = xb4[i];
        oa4[i] = make_float4(r.x + bd * xv.x, r.y + bd * xv.y,
                             r.z + bd * xv.z, r.w + bd * xv.w);
        ob4[i] = make_float4(s.x + bd * xw.x, s.y + bd * xw.y,
                             s.z + bd * xw.z, s.w + bd * xw.w);
    }
}

// ---------------------------------------------------------------------------
extern "C" void kernel_launch(void* const* d_in, const int* in_sizes, int n_in,
                              void* d_out, int out_size, void* d_ws, size_t ws_size,
                              hipStream_t stream) {
    (void)in_sizes; (void)n_in; (void)out_size; (void)ws_size;
    const float* x    = (const float*)d_in[0];
    const float* bias = (const float*)d_in[1];
    const float* W1   = (const float*)d_in[2];
    const float* b1   = (const float*)d_in[3];
    const float* W2   = (const float*)d_in[4];
    const float* b2   = (const float*)d_in[5];
    const float* W3   = (const float*)d_in[6];
    const float* b3   = (const float*)d_in[7];
    const float* Wout = (const float*)d_in[8];
    const float* freq = (const float*)d_in[9];
    float* out = (float*)d_out;

    // workspace layout (floats): Ht[64*4096] | tw[4096*2] | Kbr[1024*8192*2]
    float*  wsf = (float*)d_ws;
    float*  Ht  = wsf;                       // 262144 floats
    float2* tw  = (float2*)(wsf + 262144);   // 4096 float2
    float2* Kbr = (float2*)(wsf + 262144 + 8192);

    hipLaunchKernelGGL(tw_init_kernel, dim3(16), dim3(THREADS), 0, stream, tw);
    hipLaunchKernelGGL(mlp_kernel, dim3(SEQ / 4), dim3(THREADS), 0, stream,
                       W1, b1, W2, b2, W3, b3, freq, Ht);
    hipLaunchKernelGGL(kfft_kernel, dim3(DMODEL), dim3(THREADS), 0, stream,
                       Wout, Ht, tw, Kbr);
    hipLaunchKernelGGL(conv_kernel, dim3(DMODEL * 4), dim3(THREADS), 0, stream,
                       x, bias, Kbr, tw, out);
}

// Round 2
// 311.119 us; speedup vs baseline: 3.3899x; 3.3899x over previous
//
#include <hip/hip_runtime.h>
#include <math.h>

#define SEQ    4096
#define NFFT   8192
#define DMODEL 1024
#define ORDER  64
#define CT     512    // threads for FFT kernels
#define MLPT   256

// LDS bank-conflict swizzle: flip float-index bits [4:2] with bits [7:5].
// Preserves aligned float4 groups (bits [1:0] untouched, quads keep base%4==0).
#define SW(a)  ((a) ^ ((((a) >> 5) & 7) << 2))
#define SWQ(q) ((q) ^ (((q) >> 3) & 7))   // same swizzle on float4-quad indices

// ---------------------------------------------------------------------------
// tw[j] = e^{-2*pi*i*j/8192} = (cos th, -sin th), j in [0, 8192)
// ---------------------------------------------------------------------------
__global__ void tw_init_kernel(float2* __restrict__ tw) {
    int j = blockIdx.x * blockDim.x + threadIdx.x;
    if (j < NFFT) {
        double ang = (2.0 * M_PI / (double)NFFT) * (double)j;
        tw[j] = make_float2((float)cos(ang), (float)(-sin(ang)));
    }
}

// ---------------------------------------------------------------------------
// MLP hidden states, transposed: Ht[o][l], o<64, l<4096
// ---------------------------------------------------------------------------
__global__ void mlp_kernel(const float* __restrict__ W1, const float* __restrict__ b1,
                           const float* __restrict__ W2, const float* __restrict__ b2,
                           const float* __restrict__ W3, const float* __restrict__ b3,
                           const float* __restrict__ freq, float* __restrict__ Ht) {
    int o = threadIdx.x & 63;
    int p = threadIdx.x >> 6;          // 0..3
    int l = blockIdx.x * 4 + p;        // 0..4095
    __shared__ float hs[4][ORDER];

    float t   = (float)l / 4095.0f;
    float ang = 1e-4f * (float)(2.0 * M_PI) * (float)l / 4096.0f;
    float z0 = t, z1 = cosf(ang), z2 = -sinf(ang);
    float fo = freq[o];

    float a = z0 * W1[o] + z1 * W1[ORDER + o] + z2 * W1[2 * ORDER + o] + b1[o];
    hs[p][o] = sinf(fo * a);
    __syncthreads();

    a = b2[o];
    #pragma unroll
    for (int i = 0; i < ORDER; i++) a += hs[p][i] * W2[i * ORDER + o];
    float h2 = sinf(fo * a);
    __syncthreads();
    hs[p][o] = h2;
    __syncthreads();

    a = b3[o];
    #pragma unroll
    for (int i = 0; i < ORDER; i++) a += hs[p][i] * W3[i * ORDER + o];
    Ht[o * SEQ + l] = sinf(fo * a);
}

// ---------------------------------------------------------------------------
// Radix-4 DIF forward stage (quarter M, twiddle stride S = 2048/M).
// In-place on swizzled LDS. True DFT decomposition:
//   y0=a+c; y1=(b-id)W^j; y2=(a-c)W^2j; y3=(b+id)W^3j;  W=e^{-2pi i/(4M)}
// ---------------------------------------------------------------------------
template<int M, int S>
__device__ __forceinline__ void r4_fwd(float* re, float* im, const float2* __restrict__ tw) {
    for (int b = threadIdx.x; b < NFFT / 4; b += CT) {
        int j  = b & (M - 1);
        int i0 = ((b - j) << 2) + j;
        int s0 = SW(i0), s1 = SW(i0 + M), s2 = SW(i0 + 2 * M), s3 = SW(i0 + 3 * M);
        float x0r = re[s0], x0i = im[s0];
        float x1r = re[s1], x1i = im[s1];
        float x2r = re[s2], x2i = im[s2];
        float x3r = re[s3], x3i = im[s3];
        float ar = x0r + x2r, ai = x0i + x2i;
        float br = x0r - x2r, bi = x0i - x2i;
        float cr = x1r + x3r, ci = x1i + x3i;
        float dr = x1r - x3r, di = x1i - x3i;
        re[s0] = ar + cr;  im[s0] = ai + ci;
        float2 w1 = tw[j * S];
        float e1r = br + di, e1i = bi - dr;                 // b - i d
        re[s1] = e1r * w1.x - e1i * w1.y;
        im[s1] = e1r * w1.y + e1i * w1.x;
        float2 w2 = tw[2 * j * S];
        float e2r = ar - cr, e2i = ai - ci;
        re[s2] = e2r * w2.x - e2i * w2.y;
        im[s2] = e2r * w2.y + e2i * w2.x;
        float2 w3 = tw[3 * j * S];
        float e3r = br - di, e3i = bi + dr;                 // b + i d
        re[s3] = e3r * w3.x - e3i * w3.y;
        im[s3] = e3r * w3.y + e3i * w3.x;
    }
    __syncthreads();
}

// Exact inverse of r4_fwd (unscaled: x4 per stage).
//   y1'=y1*conj(W^j) etc.;  A=y0'+y2', B=y0'-y2', C=y1'+y3', D=y1'-y3';
//   x0=A+C; x1=B+iD; x2=A-C; x3=B-iD
template<int M, int S>
__device__ __forceinline__ void r4_inv(float* re, float* im, const float2* __restrict__ tw) {
    for (int b = threadIdx.x; b < NFFT / 4; b += CT) {
        int j  = b & (M - 1);
        int i0 = ((b - j) << 2) + j;
        int s0 = SW(i0), s1 = SW(i0 + M), s2 = SW(i0 + 2 * M), s3 = SW(i0 + 3 * M);
        float y0r = re[s0], y0i = im[s0];
        float t1r = re[s1], t1i = im[s1];
        float t2r = re[s2], t2i = im[s2];
        float t3r = re[s3], t3i = im[s3];
        float2 w1 = tw[j * S], w2 = tw[2 * j * S], w3 = tw[3 * j * S];
        // multiply by conj(w) = (w.x, -w.y)
        float y1r = t1r * w1.x + t1i * w1.y, y1i = t1i * w1.x - t1r * w1.y;
        float y2r = t2r * w2.x + t2i * w2.y, y2i = t2i * w2.x - t2r * w2.y;
        float y3r = t3r * w3.x + t3i * w3.y, y3i = t3i * w3.x - t3r * w3.y;
        float Ar = y0r + y2r, Ai = y0i + y2i;
        float Br = y0r - y2r, Bi = y0i - y2i;
        float Cr = y1r + y3r, Ci = y1i + y3i;
        float Dr = y1r - y3r, Di = y1i - y3i;
        re[s0] = Ar + Cr;  im[s0] = Ai + Ci;
        re[s1] = Br - Di;  im[s1] = Bi + Dr;   // B + iD
        re[s2] = Ar - Cr;  im[s2] = Ai - Ci;
        re[s3] = Br + Di;  im[s3] = Bi - Dr;   // B - iD
    }
    __syncthreads();
}

// ---------------------------------------------------------------------------
// Forward tail: per contiguous 8-group, radix-4 (M=2, len 8) + radix-2 (len 2),
// fully in registers; twiddles are constants (W_8 powers).
// ---------------------------------------------------------------------------
__device__ __forceinline__ void fwd_tail(float* re, float* im) {
    float4* re4 = (float4*)re;
    float4* im4 = (float4*)im;
    const float r = 0.70710678118654752f;
    for (int g = threadIdx.x; g < NFFT / 8; g += CT) {
        int q0 = SWQ(2 * g), q1 = SWQ(2 * g + 1);
        float4 ra = re4[q0], rb = re4[q1], ia = im4[q0], ib = im4[q1];
        float vr[8] = {ra.x, ra.y, ra.z, ra.w, rb.x, rb.y, rb.z, rb.w};
        float vi[8] = {ia.x, ia.y, ia.z, ia.w, ib.x, ib.y, ib.z, ib.w};
        {   // j = 0: elems 0,2,4,6, twiddles 1
            float ar = vr[0] + vr[4], ai = vi[0] + vi[4];
            float br = vr[0] - vr[4], bi = vi[0] - vi[4];
            float cr = vr[2] + vr[6], ci = vi[2] + vi[6];
            float dr = vr[2] - vr[6], di = vi[2] - vi[6];
            vr[0] = ar + cr; vi[0] = ai + ci;
            vr[2] = br + di; vi[2] = bi - dr;          // b - i d
            vr[4] = ar - cr; vi[4] = ai - ci;
            vr[6] = br - di; vi[6] = bi + dr;          // b + i d
        }
        {   // j = 1: elems 1,3,5,7, twiddles W_8^{1,2,3}
            float ar = vr[1] + vr[5], ai = vi[1] + vi[5];
            float br = vr[1] - vr[5], bi = vi[1] - vi[5];
            float cr = vr[3] + vr[7], ci = vi[3] + vi[7];
            float dr = vr[3] - vr[7], di = vi[3] - vi[7];
            vr[1] = ar + cr; vi[1] = ai + ci;
            float e1r = br + di, e1i = bi - dr;        // (b-id) * (r,-r)
            vr[3] = r * (e1r + e1i); vi[3] = r * (e1i - e1r);
            float e2r = ar - cr, e2i = ai - ci;        // (a-c) * (-i)
            vr[5] = e2i; vi[5] = -e2r;
            float e3r = br - di, e3i = bi + dr;        // (b+id) * (-r,-r)
            vr[7] = r * (e3i - e3r); vi[7] = -r * (e3r + e3i);
        }
        #pragma unroll
        for (int p = 0; p < 8; p += 2) {               // radix-2, twiddle 1
            float ur = vr[p], ui = vi[p], wr = vr[p + 1], wi = vi[p + 1];
            vr[p]     = ur + wr; vi[p]     = ui + wi;
            vr[p + 1] = ur - wr; vi[p + 1] = ui - wi;
        }
        re4[q0] = make_float4(vr[0], vr[1], vr[2], vr[3]);
        re4[q1] = make_float4(vr[4], vr[5], vr[6], vr[7]);
        im4[q0] = make_float4(vi[0], vi[1], vi[2], vi[3]);
        im4[q1] = make_float4(vi[4], vi[5], vi[6], vi[7]);
    }
    __syncthreads();
}

// Exact inverse of fwd_tail (unscaled x8 per group).
__device__ __forceinline__ void inv_head(float* re, float* im) {
    float4* re4 = (float4*)re;
    float4* im4 = (float4*)im;
    const float r = 0.70710678118654752f;
    for (int g = threadIdx.x; g < NFFT / 8; g += CT) {
        int q0 = SWQ(2 * g), q1 = SWQ(2 * g + 1);
        float4 ra = re4[q0], rb = re4[q1], ia = im4[q0], ib = im4[q1];
        float vr[8] = {ra.x, ra.y, ra.z, ra.w, rb.x, rb.y, rb.z, rb.w};
        float vi[8] = {ia.x, ia.y, ia.z, ia.w, ib.x, ib.y, ib.z, ib.w};
        #pragma unroll
        for (int p = 0; p < 8; p += 2) {               // inverse radix-2
            float ur = vr[p], ui = vi[p], wr = vr[p + 1], wi = vi[p + 1];
            vr[p]     = ur + wr; vi[p]     = ui + wi;
            vr[p + 1] = ur - wr; vi[p + 1] = ui - wi;
        }
        {   // j = 0 inverse radix-4: y' at 0,2,4,6 (twiddles 1)
            float Ar = vr[0] + vr[4], Ai = vi[0] + vi[4];
            float Br = vr[0] - vr[4], Bi = vi[0] - vi[4];
            float Cr = vr[2] + vr[6], Ci = vi[2] + vi[6];
            float Dr = vr[2] - vr[6], Di = vi[2] - vi[6];
            vr[0] = Ar + Cr; vi[0] = Ai + Ci;
            vr[2] = Br - Di; vi[2] = Bi + Dr;          // B + iD
            vr[4] = Ar - Cr; vi[4] = Ai - Ci;
            vr[6] = Br + Di; vi[6] = Bi - Dr;          // B - iD
        }
        {   // j = 1: de-twiddle with conj(W_8^{1,2,3})
            float y1r = r * (vr[3] - vi[3]), y1i = r * (vr[3] + vi[3]);   // *(r,r)
            float y2r = -vi[5],              y2i = vr[5];                 // *(0,1)=i
            float y3r = -r * (vr[7] + vi[7]), y3i = r * (vr[7] - vi[7]);  // *(-r,r)
            float Ar = vr[1] + y2r, Ai = vi[1] + y2i;
            float Br = vr[1] - y2r, Bi = vi[1] - y2i;
            float Cr = y1r + y3r,   Ci = y1i + y3i;
            float Dr = y1r - y3r,   Di = y1i - y3i;
            vr[1] = Ar + Cr; vi[1] = Ai + Ci;
            vr[3] = Br - Di; vi[3] = Bi + Dr;
            vr[5] = Ar - Cr; vi[5] = Ai - Ci;
            vr[7] = Br + Di; vi[7] = Bi - Dr;
        }
        re4[q0] = make_float4(vr[0], vr[1], vr[2], vr[3]);
        re4[q1] = make_float4(vr[4], vr[5], vr[6], vr[7]);
        im4[q0] = make_float4(vi[0], vi[1], vi[2], vi[3]);
        im4[q1] = make_float4(vi[4], vi[5], vi[6], vi[7]);
    }
    __syncthreads();
}

__device__ __forceinline__ void fft_fwd_all(float* re, float* im, const float2* __restrict__ tw) {
    r4_fwd<2048, 1>(re, im, tw);
    r4_fwd<512, 4>(re, im, tw);
    r4_fwd<128, 16>(re, im, tw);
    r4_fwd<32, 64>(re, im, tw);
    r4_fwd<8, 256>(re, im, tw);
    fwd_tail(re, im);
}

__device__ __forceinline__ void fft_inv_all(float* re, float* im, const float2* __restrict__ tw) {
    inv_head(re, im);
    r4_inv<8, 256>(re, im, tw);
    r4_inv<32, 64>(re, im, tw);
    r4_inv<128, 16>(re, im, tw);
    r4_inv<512, 4>(re, im, tw);
    r4_inv<2048, 1>(re, im, tw);
}

// ---------------------------------------------------------------------------
// Filter build + forward FFT: Kbr[d][i] in fwd digit-permuted order, * 1/N
// ---------------------------------------------------------------------------
__global__ __launch_bounds__(CT, 4) void kfft_kernel(const float* __restrict__ Wout,
                                                     const float* __restrict__ Ht,
                                                     const float2* __restrict__ tw,
                                                     float2* __restrict__ Kbr) {
    int d = blockIdx.x;
    __shared__ float re[NFFT], im[NFFT];

    const double MIN_D = -3.0701134573253944;    // log(.01)/1.5
    const double MAX_D = -15.350567286626971;    // log(.01)/0.3
    float delta = fabsf((float)(MIN_D + (MAX_D - MIN_D) * (double)d / 1023.0));

    for (int l = threadIdx.x; l < SEQ; l += CT) {
        float acc = 0.0f;
        #pragma unroll
        for (int o = 0; o < ORDER; o++)
            acc += Ht[o * SEQ + l] * Wout[o * DMODEL + d];
        float t = (float)l / 4095.0f;
        re[SW(l)] = acc * expf(-t * delta);
        im[SW(l)] = 0.0f;
        re[SW(l + SEQ)] = 0.0f;
        im[SW(l + SEQ)] = 0.0f;
    }
    __syncthreads();

    fft_fwd_all(re, im, tw);

    const float scale = 1.0f / (float)NFFT;
    for (int i = threadIdx.x; i < NFFT; i += CT) {
        Kbr[(size_t)d * NFFT + i] = make_float2(re[SW(i)] * scale, im[SW(i)] * scale);
    }
}

// ---------------------------------------------------------------------------
// Main conv: one WG per (channel, batch-pair); z = x[b0] + i x[b1]
// ---------------------------------------------------------------------------
__global__ __launch_bounds__(CT, 4) void conv_kernel(const float* __restrict__ x,
                                                     const float* __restrict__ bias,
                                                     const float2* __restrict__ Kbr,
                                                     const float2* __restrict__ tw,
                                                     float* __restrict__ out) {
    int wg   = blockIdx.x;            // 0..4095
    int d    = wg & (DMODEL - 1);
    int pair = wg >> 10;              // 0..3
    int b0   = 2 * pair, b1 = 2 * pair + 1;

    const float* xa = x + ((size_t)b0 * DMODEL + d) * SEQ;
    const float* xb = x + ((size_t)b1 * DMODEL + d) * SEQ;

    __shared__ float re[NFFT], im[NFFT];
    float4* re4 = (float4*)re;
    float4* im4 = (float4*)im;
    const float4* xa4 = (const float4*)xa;
    const float4* xb4 = (const float4*)xb;

    float4 z4 = make_float4(0.f, 0.f, 0.f, 0.f);
    for (int q = threadIdx.x; q < SEQ / 4; q += CT) {
        re4[SWQ(q)] = xa4[q];
        im4[SWQ(q)] = xb4[q];
        re4[SWQ(q + SEQ / 4)] = z4;
        im4[SWQ(q + SEQ / 4)] = z4;
    }
    __syncthreads();

    fft_fwd_all(re, im, tw);

    const float2* K = Kbr + (size_t)d * NFFT;
    for (int i = threadIdx.x; i < NFFT; i += CT) {
        float2 k2 = K[i];
        int s = SW(i);
        float zr = re[s], zi = im[s];
        re[s] = zr * k2.x - zi * k2.y;
        im[s] = zr * k2.y + zi * k2.x;
    }
    __syncthreads();

    fft_inv_all(re, im, tw);

    float bd = bias[d];
    float4* oa4 = (float4*)(out + ((size_t)b0 * DMODEL + d) * SEQ);
    float4* ob4 = (float4*)(out + ((size_t)b1 * DMODEL + d) * SEQ);
    for (int q = threadIdx.x; q < SEQ / 4; q += CT) {
        int sq = SWQ(q);
        float4 rr = re4[sq], xv = xa4[q];
        float4 ss = im4[sq], xw = xb4[q];
        oa4[q] = make_float4(rr.x + bd * xv.x, rr.y + bd * xv.y,
                             rr.z + bd * xv.z, rr.w + bd * xv.w);
        ob4[q] = make_float4(ss.x + bd * xw.x, ss.y + bd * xw.y,
                             ss.z + bd * xw.z, ss.w + bd * xw.w);
    }
}

// ---------------------------------------------------------------------------
extern "C" void kernel_launch(void* const* d_in, const int* in_sizes, int n_in,
                              void* d_out, int out_size, void* d_ws, size_t ws_size,
                              hipStream_t stream) {
    (void)in_sizes; (void)n_in; (void)out_size; (void)ws_size;
    const float* x    = (const float*)d_in[0];
    const float* bias = (const float*)d_in[1];
    const float* W1   = (const float*)d_in[2];
    const float* b1   = (const float*)d_in[3];
    const float* W2   = (const float*)d_in[4];
    const float* b2   = (const float*)d_in[5];
    const float* W3   = (const float*)d_in[6];
    const float* b3   = (const float*)d_in[7];
    const float* Wout = (const float*)d_in[8];
    const float* freq = (const float*)d_in[9];
    float* out = (float*)d_out;

    // ws layout (floats): Ht[64*4096] | tw[8192 float2] | Kbr[1024*8192 float2]
    float*  wsf = (float*)d_ws;
    float*  Ht  = wsf;                        // 262144 floats
    float2* tw  = (float2*)(wsf + 262144);    // 8192 float2
    float2* Kbr = (float2*)(wsf + 262144 + 16384);

    hipLaunchKernelGGL(tw_init_kernel, dim3(NFFT / MLPT), dim3(MLPT), 0, stream, tw);
    hipLaunchKernelGGL(mlp_kernel, dim3(SEQ / 4), dim3(MLPT), 0, stream,
                       W1, b1, W2, b2, W3, b3, freq, Ht);
    hipLaunchKernelGGL(kfft_kernel, dim3(DMODEL), dim3(CT), 0, stream,
                       Wout, Ht, tw, Kbr);
    hipLaunchKernelGGL(conv_kernel, dim3(DMODEL * 4), dim3(CT), 0, stream,
                       x, bias, Kbr, tw, out);
}